// Round 1
// baseline (214.423 us; speedup 1.0000x reference)
//
#include <hip/hip_runtime.h>

typedef __attribute__((ext_vector_type(8))) short short8;
typedef __attribute__((ext_vector_type(4))) float f32x4;

#define S_DIM 8192
#define H_DIM 4096
#define A_DIM 1024
#define BK 32
#define LDSW 40   // shorts per LDS row: 32 data + 8 pad = 80 B (16B-aligned, even bank spread)

__device__ __forceinline__ short f2bf(float x) {
  unsigned u = __float_as_uint(x);
  u += 0x7fffu + ((u >> 16) & 1u);   // round-to-nearest-even
  return (short)(u >> 16);
}

// K1: comb[a] = hidden . W_w[a] + W_b[a] + U_b[a]   (one wave per row)
__global__ __launch_bounds__(256) void comb_kernel(const float* __restrict__ hidden,
                                                   const float* __restrict__ Ww,
                                                   const float* __restrict__ Wb,
                                                   const float* __restrict__ Ub,
                                                   float* __restrict__ comb) {
  const int wave = threadIdx.x >> 6;
  const int lane = threadIdx.x & 63;
  const int a = blockIdx.x * 4 + wave;
  const float* row = Ww + (size_t)a * H_DIM;
  float acc = 0.f;
  for (int k = lane * 4; k < H_DIM; k += 64 * 4) {
    float4 w = *(const float4*)(row + k);
    float4 h = *(const float4*)(hidden + k);
    acc += w.x * h.x + w.y * h.y + w.z * h.z + w.w * h.w;
  }
  #pragma unroll
  for (int mk = 1; mk < 64; mk <<= 1) acc += __shfl_xor(acc, mk);
  if (lane == 0) comb[a] = acc + Wb[a] + Ub[a];
}

// K2: bf16 MFMA GEMM (M=S, N=A, K=H), fused tanh + V_w reduction -> atomicAdd(scores)
__global__ __launch_bounds__(256) void gemm_score_kernel(const float* __restrict__ E,
                                                         const float* __restrict__ Uw,
                                                         const float* __restrict__ comb,
                                                         const float* __restrict__ Vw,
                                                         float* __restrict__ scores) {
  __shared__ __align__(16) short sA[128 * LDSW];
  __shared__ __align__(16) short sB[128 * LDSW];

  const int tid  = threadIdx.x;
  const int lane = tid & 63;
  const int wave = tid >> 6;
  const int wm = wave >> 1, wn = wave & 1;     // 2x2 waves, each 64x64 out
  const int m0 = blockIdx.x * 128;
  const int n0 = blockIdx.y * 128;

  // staging: thread -> (row sr, 16-float half sh)
  const int sr = tid >> 1;
  const int sh = tid & 1;
  const float* gA = E  + (size_t)(m0 + sr) * H_DIM + sh * 16;
  const float* gB = Uw + (size_t)(n0 + sr) * H_DIM + sh * 16;

  alignas(16) float fa[16], fb[16];
  #pragma unroll
  for (int j = 0; j < 4; ++j) {
    *(float4*)&fa[j * 4] = *(const float4*)(gA + j * 4);
    *(float4*)&fb[j * 4] = *(const float4*)(gB + j * 4);
  }

  f32x4 acc[4][4];
  const f32x4 zero = {0.f, 0.f, 0.f, 0.f};
  #pragma unroll
  for (int i = 0; i < 4; ++i)
    #pragma unroll
    for (int j = 0; j < 4; ++j) acc[i][j] = zero;

  short* wA = &sA[sr * LDSW + sh * 16];
  short* wB = &sB[sr * LDSW + sh * 16];
  const int NK = H_DIM / BK;   // 128

  for (int kt = 0; kt < NK; ++kt) {
    // convert current staged tile (regs) to bf16
    short8 ca0, ca1, cb0, cb1;
    #pragma unroll
    for (int j = 0; j < 8; ++j) {
      ca0[j] = f2bf(fa[j]);     ca1[j] = f2bf(fa[8 + j]);
      cb0[j] = f2bf(fb[j]);     cb1[j] = f2bf(fb[8 + j]);
    }
    __syncthreads();                       // prev iteration's reads done
    *(short8*)(wA)     = ca0;
    *(short8*)(wA + 8) = ca1;
    *(short8*)(wB)     = cb0;
    *(short8*)(wB + 8) = cb1;
    __syncthreads();                       // tile visible

    if (kt + 1 < NK) {                     // prefetch next tile under MFMA
      const float* pA = gA + (kt + 1) * BK;
      const float* pB = gB + (kt + 1) * BK;
      #pragma unroll
      for (int j = 0; j < 4; ++j) {
        *(float4*)&fa[j * 4] = *(const float4*)(pA + j * 4);
        *(float4*)&fb[j * 4] = *(const float4*)(pB + j * 4);
      }
    }

    short8 af[4], bfr[4];
    #pragma unroll
    for (int i = 0; i < 4; ++i)
      af[i] = *(const short8*)&sA[(wm * 64 + i * 16 + (lane & 15)) * LDSW + (lane >> 4) * 8];
    #pragma unroll
    for (int j = 0; j < 4; ++j)
      bfr[j] = *(const short8*)&sB[(wn * 64 + j * 16 + (lane & 15)) * LDSW + (lane >> 4) * 8];

    #pragma unroll
    for (int i = 0; i < 4; ++i)
      #pragma unroll
      for (int j = 0; j < 4; ++j)
        acc[i][j] = __builtin_amdgcn_mfma_f32_16x16x32_bf16(af[i], bfr[j], acc[i][j], 0, 0, 0);
  }

  // epilogue: scores[s] += sum_cols Vw[a] * tanh(C + comb[a])
  float vwv[4], cbv[4];
  #pragma unroll
  for (int j = 0; j < 4; ++j) {
    const int col = n0 + wn * 64 + j * 16 + (lane & 15);
    vwv[j] = Vw[col];
    cbv[j] = comb[col];
  }
  #pragma unroll
  for (int i = 0; i < 4; ++i) {
    #pragma unroll
    for (int r = 0; r < 4; ++r) {
      float s = 0.f;
      #pragma unroll
      for (int j = 0; j < 4; ++j)
        s += vwv[j] * tanhf(acc[i][j][r] + cbv[j]);
      s += __shfl_xor(s, 1);
      s += __shfl_xor(s, 2);
      s += __shfl_xor(s, 4);
      s += __shfl_xor(s, 8);               // reduce over 16 cols (C layout: col=lane&15)
      if ((lane & 15) == 0) {
        const int grow = m0 + wm * 64 + i * 16 + (lane >> 4) * 4 + r;
        atomicAdd(&scores[grow], s);
      }
    }
  }
}

// K3: softmax over 8192 scores -> attn
__global__ __launch_bounds__(1024) void softmax_kernel(const float* __restrict__ scores,
                                                       float* __restrict__ attn) {
  __shared__ float redm[16];
  __shared__ float reds[16];
  const int tid = threadIdx.x;
  const int lane = tid & 63, wid = tid >> 6;
  float v[8];
  float m = -3.0e38f;
  #pragma unroll
  for (int i = 0; i < 8; ++i) { v[i] = scores[i * 1024 + tid]; m = fmaxf(m, v[i]); }
  #pragma unroll
  for (int mk = 1; mk < 64; mk <<= 1) m = fmaxf(m, __shfl_xor(m, mk));
  if (lane == 0) redm[wid] = m;
  __syncthreads();
  float M = redm[0];
  #pragma unroll
  for (int j = 1; j < 16; ++j) M = fmaxf(M, redm[j]);
  float e[8]; float s = 0.f;
  #pragma unroll
  for (int i = 0; i < 8; ++i) { e[i] = __expf(v[i] - M); s += e[i]; }
  #pragma unroll
  for (int mk = 1; mk < 64; mk <<= 1) s += __shfl_xor(s, mk);
  if (lane == 0) reds[wid] = s;
  __syncthreads();
  float T = 0.f;
  #pragma unroll
  for (int j = 0; j < 16; ++j) T += reds[j];
  const float inv = 1.f / T;
  #pragma unroll
  for (int i = 0; i < 8; ++i) attn[i * 1024 + tid] = e[i] * inv;
}

// K4: context[h] = sum_s attn[s] * E[s,h]  (S split into 32 chunks, atomicAdd)
__global__ __launch_bounds__(256) void context_kernel(const float* __restrict__ E,
                                                      const float* __restrict__ attn,
                                                      float* __restrict__ out) {
  const int h  = blockIdx.x * 256 + threadIdx.x;
  const int s0 = blockIdx.y * 256;
  float acc = 0.f;
  #pragma unroll 4
  for (int s = s0; s < s0 + 256; ++s)
    acc += attn[s] * E[(size_t)s * H_DIM + h];
  atomicAdd(&out[h], acc);
}

extern "C" void kernel_launch(void* const* d_in, const int* in_sizes, int n_in,
                              void* d_out, int out_size, void* d_ws, size_t ws_size,
                              hipStream_t stream) {
  const float* E   = (const float*)d_in[0];
  const float* hid = (const float*)d_in[1];
  const float* Uw  = (const float*)d_in[2];
  const float* Ub  = (const float*)d_in[3];
  const float* Ww  = (const float*)d_in[4];
  const float* Wb  = (const float*)d_in[5];
  const float* Vw  = (const float*)d_in[6];
  // d_in[7] = V_b: softmax is shift-invariant -> unused

  float* out    = (float*)d_out;
  float* ws     = (float*)d_ws;
  float* comb   = ws;                  // 1024 f32
  float* scores = ws + 1024;           // 8192 f32 (atomic target, must be zeroed per call)
  float* attn   = ws + 1024 + 8192;    // 8192 f32

  hipMemsetAsync(scores, 0, S_DIM * sizeof(float), stream);
  hipMemsetAsync(out, 0, (size_t)out_size * sizeof(float), stream);

  comb_kernel<<<A_DIM / 4, 256, 0, stream>>>(hid, Ww, Wb, Ub, comb);

  dim3 grid(S_DIM / 128, A_DIM / 128);
  gemm_score_kernel<<<grid, 256, 0, stream>>>(E, Uw, comb, Vw, scores);

  softmax_kernel<<<1, 1024, 0, stream>>>(scores, attn);

  context_kernel<<<dim3(H_DIM / 256, 32), 256, 0, stream>>>(E, attn, out);
}

// Round 2
// 156.656 us; speedup vs baseline: 1.3688x; 1.3688x over previous
//
#include <hip/hip_runtime.h>

typedef __attribute__((ext_vector_type(8))) short short8;
typedef __attribute__((ext_vector_type(4))) float f32x4;

#define S_DIM 8192
#define H_DIM 4096
#define A_DIM 1024

__device__ __forceinline__ short f2bf(float x) {
  unsigned u = __float_as_uint(x);
  u += 0x7fffu + ((u >> 16) & 1u);   // round-to-nearest-even
  return (short)(u >> 16);
}

__device__ __forceinline__ float bf2f(short b) {
  return __uint_as_float(((unsigned)(unsigned short)b) << 16);
}

__device__ __forceinline__ void gload16(const void* g, void* l) {
  __builtin_amdgcn_global_load_lds(
      (const __attribute__((address_space(1))) void*)g,
      (__attribute__((address_space(3))) void*)l, 16, 0, 0);
}

// ---------------- shared kernels ----------------

// K1: comb[a] = hidden . W_w[a] + W_b[a] + U_b[a]   (one wave per row)
__global__ __launch_bounds__(256) void comb_kernel(const float* __restrict__ hidden,
                                                   const float* __restrict__ Ww,
                                                   const float* __restrict__ Wb,
                                                   const float* __restrict__ Ub,
                                                   float* __restrict__ comb) {
  const int wave = threadIdx.x >> 6;
  const int lane = threadIdx.x & 63;
  const int a = blockIdx.x * 4 + wave;
  const float* row = Ww + (size_t)a * H_DIM;
  float acc = 0.f;
  for (int k = lane * 4; k < H_DIM; k += 64 * 4) {
    float4 w = *(const float4*)(row + k);
    float4 h = *(const float4*)(hidden + k);
    acc += w.x * h.x + w.y * h.y + w.z * h.z + w.w * h.w;
  }
  #pragma unroll
  for (int mk = 1; mk < 64; mk <<= 1) acc += __shfl_xor(acc, mk);
  if (lane == 0) comb[a] = acc + Wb[a] + Ub[a];
}

// K3: softmax over 8192 scores -> attn (single block)
__global__ __launch_bounds__(1024) void softmax_kernel(const float* __restrict__ scores,
                                                       float* __restrict__ attn) {
  __shared__ float redm[16];
  __shared__ float reds[16];
  const int tid = threadIdx.x;
  const int lane = tid & 63, wid = tid >> 6;
  float v[8];
  float m = -3.0e38f;
  #pragma unroll
  for (int i = 0; i < 8; ++i) { v[i] = scores[i * 1024 + tid]; m = fmaxf(m, v[i]); }
  #pragma unroll
  for (int mk = 1; mk < 64; mk <<= 1) m = fmaxf(m, __shfl_xor(m, mk));
  if (lane == 0) redm[wid] = m;
  __syncthreads();
  float M = redm[0];
  #pragma unroll
  for (int j = 1; j < 16; ++j) M = fmaxf(M, redm[j]);
  float e[8]; float s = 0.f;
  #pragma unroll
  for (int i = 0; i < 8; ++i) { e[i] = __expf(v[i] - M); s += e[i]; }
  #pragma unroll
  for (int mk = 1; mk < 64; mk <<= 1) s += __shfl_xor(s, mk);
  if (lane == 0) reds[wid] = s;
  __syncthreads();
  float T = 0.f;
  #pragma unroll
  for (int j = 0; j < 16; ++j) T += reds[j];
  const float inv = 1.f / T;
  #pragma unroll
  for (int i = 0; i < 8; ++i) attn[i * 1024 + tid] = e[i] * inv;
}

// ---------------- fast path (bf16 pre-convert + global_load_lds GEMM) ----------------

// K0: fp32 -> bf16 bulk convert (n8 = elements/8)
__global__ __launch_bounds__(256) void cvt_kernel(const float* __restrict__ src,
                                                  unsigned short* __restrict__ dst,
                                                  int n8) {
  const int stride = gridDim.x * blockDim.x;
  for (int i = blockIdx.x * blockDim.x + threadIdx.x; i < n8; i += stride) {
    float4 a = ((const float4*)src)[(size_t)i * 2];
    float4 b = ((const float4*)src)[(size_t)i * 2 + 1];
    short8 o;
    o[0] = f2bf(a.x); o[1] = f2bf(a.y); o[2] = f2bf(a.z); o[3] = f2bf(a.w);
    o[4] = f2bf(b.x); o[5] = f2bf(b.y); o[6] = f2bf(b.z); o[7] = f2bf(b.w);
    ((short8*)dst)[i] = o;
  }
}

// K2: bf16 MFMA GEMM (M=S, N=A, K=H), m97 structure: global_load_lds staging,
// 128x128 tile, BK=64, 2 barriers/K-step. Fused tanh + V_w reduce -> atomicAdd.
__global__ __launch_bounds__(256) void gemm_score_bf_kernel(
    const unsigned short* __restrict__ A,   // Ebf  [S][H]
    const unsigned short* __restrict__ B,   // Uwbf [A][H]
    const float* __restrict__ comb,
    const float* __restrict__ Vw,
    float* __restrict__ scores) {
  __shared__ __align__(16) unsigned short sA[128 * 64];   // 16 KB
  __shared__ __align__(16) unsigned short sB[128 * 64];   // 16 KB

  const int tid  = threadIdx.x;
  const int lane = tid & 63;
  const int wave = tid >> 6;
  const int wm = wave >> 1, wn = wave & 1;
  const int m0 = blockIdx.x * 128;
  const int n0 = blockIdx.y * 128;

  // staging: wave w, instr i -> LDS rows w*32+i*8 .. +7 ; lane l -> row +(l>>3), 16B chunk (l&7)
  const int srow = wave * 32 + (lane >> 3);
  const int scol = (lane & 7) * 8;
  const unsigned short* ga = A + (size_t)(m0 + srow) * H_DIM + scol;
  const unsigned short* gb = B + (size_t)(n0 + srow) * H_DIM + scol;

  #define STAGE(kt) do {                                                     \
    const unsigned short* pa_ = ga + (size_t)(kt) * 64;                      \
    const unsigned short* pb_ = gb + (size_t)(kt) * 64;                      \
    _Pragma("unroll")                                                        \
    for (int i_ = 0; i_ < 4; ++i_) {                                         \
      gload16(pa_ + (size_t)i_ * 8 * H_DIM, &sA[(wave * 4 + i_) * 512]);     \
      gload16(pb_ + (size_t)i_ * 8 * H_DIM, &sB[(wave * 4 + i_) * 512]);     \
    }                                                                        \
  } while (0)

  f32x4 acc[4][4];
  const f32x4 zero = {0.f, 0.f, 0.f, 0.f};
  #pragma unroll
  for (int i = 0; i < 4; ++i)
    #pragma unroll
    for (int j = 0; j < 4; ++j) acc[i][j] = zero;

  STAGE(0);

  const int NK = H_DIM / 64;   // 64
  for (int kt = 0; kt < NK; ++kt) {
    __syncthreads();           // vmcnt drained -> tile kt resident

    short8 af[2][4], bfr[2][4];
    #pragma unroll
    for (int ks = 0; ks < 2; ++ks) {
      #pragma unroll
      for (int i = 0; i < 4; ++i)
        af[ks][i] = *(const short8*)&sA[(wm * 64 + i * 16 + (lane & 15)) * 64 + ks * 32 + (lane >> 4) * 8];
      #pragma unroll
      for (int j = 0; j < 4; ++j)
        bfr[ks][j] = *(const short8*)&sB[(wn * 64 + j * 16 + (lane & 15)) * 64 + ks * 32 + (lane >> 4) * 8];
    }
    __syncthreads();           // all reads done; safe to overwrite

    if (kt + 1 < NK) STAGE(kt + 1);   // in flight under MFMA

    #pragma unroll
    for (int ks = 0; ks < 2; ++ks)
      #pragma unroll
      for (int i = 0; i < 4; ++i)
        #pragma unroll
        for (int j = 0; j < 4; ++j)
          acc[i][j] = __builtin_amdgcn_mfma_f32_16x16x32_bf16(af[ks][i], bfr[ks][j], acc[i][j], 0, 0, 0);
  }
  #undef STAGE

  // epilogue: scores[s] += sum_cols Vw[a] * tanh(C + comb[a])
  float vwv[4], cbv[4];
  #pragma unroll
  for (int j = 0; j < 4; ++j) {
    const int col = n0 + wn * 64 + j * 16 + (lane & 15);
    vwv[j] = Vw[col];
    cbv[j] = comb[col];
  }
  #pragma unroll
  for (int i = 0; i < 4; ++i) {
    #pragma unroll
    for (int r = 0; r < 4; ++r) {
      float s = 0.f;
      #pragma unroll
      for (int j = 0; j < 4; ++j)
        s += vwv[j] * tanhf(acc[i][j][r] + cbv[j]);
      s += __shfl_xor(s, 1);
      s += __shfl_xor(s, 2);
      s += __shfl_xor(s, 4);
      s += __shfl_xor(s, 8);
      if ((lane & 15) == 0) {
        const int grow = m0 + wm * 64 + i * 16 + (lane >> 4) * 4 + r;
        atomicAdd(&scores[grow], s);
      }
    }
  }
}

// K4a: partial[y][h] = sum over 64-row chunk of attn[s]*Ebf[s][h], 8 cols/thread
__global__ __launch_bounds__(256) void context_bf_kernel(const unsigned short* __restrict__ Ebf,
                                                         const float* __restrict__ attn,
                                                         float* __restrict__ partial) {
  const int h0 = (blockIdx.x * 256 + threadIdx.x) * 8;
  const int s0 = blockIdx.y * 64;
  float acc[8] = {0.f, 0.f, 0.f, 0.f, 0.f, 0.f, 0.f, 0.f};
  for (int s = s0; s < s0 + 64; ++s) {
    const float w = attn[s];
    short8 e = *(const short8*)(Ebf + (size_t)s * H_DIM + h0);
    #pragma unroll
    for (int j = 0; j < 8; ++j) acc[j] += w * bf2f(e[j]);
  }
  float* p = partial + (size_t)blockIdx.y * H_DIM + h0;
  #pragma unroll
  for (int j = 0; j < 8; ++j) p[j] = acc[j];
}

// K4b: out[h] = sum_y partial[y][h]
__global__ __launch_bounds__(256) void context_reduce_kernel(const float* __restrict__ partial,
                                                             float* __restrict__ out) {
  const int h = blockIdx.x * 256 + threadIdx.x;
  float acc = 0.f;
  #pragma unroll 8
  for (int y = 0; y < 128; ++y) acc += partial[(size_t)y * H_DIM + h];
  out[h] = acc;
}

// ---------------- fallback path (R1: fused fp32->bf16 staging GEMM) ----------------

#define LDSW 40
__global__ __launch_bounds__(256) void gemm_score_kernel(const float* __restrict__ E,
                                                         const float* __restrict__ Uw,
                                                         const float* __restrict__ comb,
                                                         const float* __restrict__ Vw,
                                                         float* __restrict__ scores) {
  __shared__ __align__(16) short sA[128 * LDSW];
  __shared__ __align__(16) short sB[128 * LDSW];
  const int tid  = threadIdx.x;
  const int lane = tid & 63;
  const int wave = tid >> 6;
  const int wm = wave >> 1, wn = wave & 1;
  const int m0 = blockIdx.x * 128;
  const int n0 = blockIdx.y * 128;
  const int sr = tid >> 1;
  const int sh = tid & 1;
  const float* gA = E  + (size_t)(m0 + sr) * H_DIM + sh * 16;
  const float* gB = Uw + (size_t)(n0 + sr) * H_DIM + sh * 16;
  alignas(16) float fa[16], fb[16];
  #pragma unroll
  for (int j = 0; j < 4; ++j) {
    *(float4*)&fa[j * 4] = *(const float4*)(gA + j * 4);
    *(float4*)&fb[j * 4] = *(const float4*)(gB + j * 4);
  }
  f32x4 acc[4][4];
  const f32x4 zero = {0.f, 0.f, 0.f, 0.f};
  #pragma unroll
  for (int i = 0; i < 4; ++i)
    #pragma unroll
    for (int j = 0; j < 4; ++j) acc[i][j] = zero;
  short* wA = &sA[sr * LDSW + sh * 16];
  short* wB = &sB[sr * LDSW + sh * 16];
  const int NK = H_DIM / 32;
  for (int kt = 0; kt < NK; ++kt) {
    short8 ca0, ca1, cb0, cb1;
    #pragma unroll
    for (int j = 0; j < 8; ++j) {
      ca0[j] = f2bf(fa[j]);     ca1[j] = f2bf(fa[8 + j]);
      cb0[j] = f2bf(fb[j]);     cb1[j] = f2bf(fb[8 + j]);
    }
    __syncthreads();
    *(short8*)(wA)     = ca0;
    *(short8*)(wA + 8) = ca1;
    *(short8*)(wB)     = cb0;
    *(short8*)(wB + 8) = cb1;
    __syncthreads();
    if (kt + 1 < NK) {
      const float* pA = gA + (kt + 1) * 32;
      const float* pB = gB + (kt + 1) * 32;
      #pragma unroll
      for (int j = 0; j < 4; ++j) {
        *(float4*)&fa[j * 4] = *(const float4*)(pA + j * 4);
        *(float4*)&fb[j * 4] = *(const float4*)(pB + j * 4);
      }
    }
    short8 af[4], bfr[4];
    #pragma unroll
    for (int i = 0; i < 4; ++i)
      af[i] = *(const short8*)&sA[(wm * 64 + i * 16 + (lane & 15)) * LDSW + (lane >> 4) * 8];
    #pragma unroll
    for (int j = 0; j < 4; ++j)
      bfr[j] = *(const short8*)&sB[(wn * 64 + j * 16 + (lane & 15)) * LDSW + (lane >> 4) * 8];
    #pragma unroll
    for (int i = 0; i < 4; ++i)
      #pragma unroll
      for (int j = 0; j < 4; ++j)
        acc[i][j] = __builtin_amdgcn_mfma_f32_16x16x32_bf16(af[i], bfr[j], acc[i][j], 0, 0, 0);
  }
  float vwv[4], cbv[4];
  #pragma unroll
  for (int j = 0; j < 4; ++j) {
    const int col = n0 + wn * 64 + j * 16 + (lane & 15);
    vwv[j] = Vw[col];
    cbv[j] = comb[col];
  }
  #pragma unroll
  for (int i = 0; i < 4; ++i) {
    #pragma unroll
    for (int r = 0; r < 4; ++r) {
      float s = 0.f;
      #pragma unroll
      for (int j = 0; j < 4; ++j)
        s += vwv[j] * tanhf(acc[i][j][r] + cbv[j]);
      s += __shfl_xor(s, 1);
      s += __shfl_xor(s, 2);
      s += __shfl_xor(s, 4);
      s += __shfl_xor(s, 8);
      if ((lane & 15) == 0) {
        const int grow = m0 + wm * 64 + i * 16 + (lane >> 4) * 4 + r;
        atomicAdd(&scores[grow], s);
      }
    }
  }
}

__global__ __launch_bounds__(256) void context_kernel(const float* __restrict__ E,
                                                      const float* __restrict__ attn,
                                                      float* __restrict__ out) {
  const int h  = blockIdx.x * 256 + threadIdx.x;
  const int s0 = blockIdx.y * 256;
  float acc = 0.f;
  #pragma unroll 4
  for (int s = s0; s < s0 + 256; ++s)
    acc += attn[s] * E[(size_t)s * H_DIM + h];
  atomicAdd(&out[h], acc);
}

// ---------------- launch ----------------

extern "C" void kernel_launch(void* const* d_in, const int* in_sizes, int n_in,
                              void* d_out, int out_size, void* d_ws, size_t ws_size,
                              hipStream_t stream) {
  const float* E   = (const float*)d_in[0];
  const float* hid = (const float*)d_in[1];
  const float* Uw  = (const float*)d_in[2];
  const float* Ub  = (const float*)d_in[3];
  const float* Ww  = (const float*)d_in[4];
  const float* Wb  = (const float*)d_in[5];
  const float* Vw  = (const float*)d_in[6];
  // d_in[7] = V_b: softmax shift-invariant -> unused

  float* out    = (float*)d_out;
  float* ws     = (float*)d_ws;
  float* comb   = ws;                       // 1024 f32
  float* scores = ws + 1024;                // 8192 f32
  float* attn   = ws + 1024 + 8192;         // 8192 f32

  // fast-path scratch: partial [128][4096] f32, Ebf [S][H] bf16, Uwbf [A][H] bf16
  float* partial = ws + 17408;
  unsigned short* Ebf  = (unsigned short*)(ws + 17408 + 128 * H_DIM);
  unsigned short* Uwbf = Ebf + (size_t)S_DIM * H_DIM;
  const size_t NEED = (size_t)(17408 + 128 * H_DIM) * 4
                    + (size_t)(S_DIM + A_DIM) * H_DIM * 2;

  hipMemsetAsync(scores, 0, S_DIM * sizeof(float), stream);

  comb_kernel<<<A_DIM / 4, 256, 0, stream>>>(hid, Ww, Wb, Ub, comb);

  if (ws_size >= NEED) {
    cvt_kernel<<<2048, 256, 0, stream>>>(E, Ebf, (int)((size_t)S_DIM * H_DIM / 8));
    cvt_kernel<<<512, 256, 0, stream>>>(Uw, Uwbf, (int)((size_t)A_DIM * H_DIM / 8));

    dim3 grid(S_DIM / 128, A_DIM / 128);
    gemm_score_bf_kernel<<<grid, 256, 0, stream>>>(Ebf, Uwbf, comb, Vw, scores);

    softmax_kernel<<<1, 1024, 0, stream>>>(scores, attn);

    context_bf_kernel<<<dim3(H_DIM / 2048, S_DIM / 64), 256, 0, stream>>>(Ebf, attn, partial);
    context_reduce_kernel<<<H_DIM / 256, 256, 0, stream>>>(partial, out);
  } else {
    hipMemsetAsync(out, 0, (size_t)out_size * sizeof(float), stream);
    dim3 grid(S_DIM / 128, A_DIM / 128);
    gemm_score_kernel<<<grid, 256, 0, stream>>>(E, Uw, comb, Vw, scores);
    softmax_kernel<<<1, 1024, 0, stream>>>(scores, attn);
    context_kernel<<<dim3(H_DIM / 256, 32), 256, 0, stream>>>(E, attn, out);
  }
}